// Round 2
// 366.697 us; speedup vs baseline: 1.0238x; 1.0238x over previous
//
#include <hip/hip_runtime.h>
#include <math.h>

// Problem: B=512, S=4096, H=32, D=16
// q = enc @ WqT + bq via one mfma_f32_16x16x32_bf16 per 16 rows (K=32=H),
// with OPERANDS SWAPPED (A=Wq, B=enc) so acc[r] = q[d=quad*4+r][row=l15]:
// the d-reduction for ||q|| and q.kn is 8 in-register FMAs + 2 bpermute
// butterfly stages instead of 8x red16 DPP trees.
// Barrier-free streaming, depth-4 register pipeline, 8 waves/block
// (4 waves/SIMD at 2 blocks/CU) for latency hiding.
#define BB    512
#define SS    4096
#define HH    32
#define DD    16
#define NT    512                          // 8 waves/block, one block per batch row
#define WAVES 8
#define RPW   (SS / WAVES)                 // 512 rows per wave
#define TPW   (RPW / 16)                   // 32 MFMA tiles per wave
#define DEPTH 4                            // register pipeline depth (tiles)
#define NGRP  (TPW / DEPTH)                // 8 groups
#define EPSI  1e-8f

typedef __attribute__((ext_vector_type(8))) short   short8;   // 8 bf16 = 4 VGPR
typedef __attribute__((ext_vector_type(4))) float   floatx4;  // MFMA acc

// VALU-only cross-lane add within each 16-lane DPP row (setup only)
template <int CTRL>
__device__ __forceinline__ float dpp_add(float x) {
    int xi = __builtin_bit_cast(int, x);
    int yi = __builtin_amdgcn_update_dpp(0, xi, CTRL, 0xF, 0xF, true);
    return x + __builtin_bit_cast(float, yi);
}
__device__ __forceinline__ float red16(float x) {
    x = dpp_add<0xB1>(x);    // quad_perm ^1
    x = dpp_add<0x4E>(x);    // quad_perm ^2
    x = dpp_add<0x141>(x);   // row_half_mirror
    x = dpp_add<0x140>(x);   // row_mirror
    return x;                // all 16 lanes hold the row total
}

// 8x fp32 -> bf16 RNE via v_cvt_pk_bf16_f32 (same rounding as manual RNE)
__device__ __forceinline__ short8 cvt_bf16x8(float4 a, float4 b) {
    unsigned p0, p1, p2, p3;
    asm("v_cvt_pk_bf16_f32 %0, %1, %2" : "=&v"(p0) : "v"(a.x), "v"(a.y));
    asm("v_cvt_pk_bf16_f32 %0, %1, %2" : "=&v"(p1) : "v"(a.z), "v"(a.w));
    asm("v_cvt_pk_bf16_f32 %0, %1, %2" : "=&v"(p2) : "v"(b.x), "v"(b.y));
    asm("v_cvt_pk_bf16_f32 %0, %1, %2" : "=&v"(p3) : "v"(b.z), "v"(b.w));
    union { unsigned u[4]; short8 s; } r;
    r.u[0] = p0; r.u[1] = p1; r.u[2] = p2; r.u[3] = p3;
    return r.s;
}

// x + value-from-lane (addr = (lane^k)<<2, precomputed)
__device__ __forceinline__ float bperm_add(int addr, float x) {
    int xi = __builtin_bit_cast(int, x);
    int yi = __builtin_amdgcn_ds_bpermute(addr, xi);
    return x + __builtin_bit_cast(float, yi);
}

__global__ __launch_bounds__(NT, 4)
void attn_cos_logsoftmax(const float* __restrict__ dec,   // [B,H]
                         const float* __restrict__ enc,   // [B,S,H]
                         const float* __restrict__ Wq,    // [D,H]
                         const float* __restrict__ bq,    // [D]
                         const float* __restrict__ Wk,    // [D,H]
                         const float* __restrict__ bk,    // [D]
                         float* __restrict__ out)         // [B,1,S]
{
    __shared__ float attS[SS];            // 16 KB attention logits
    __shared__ float redM[WAVES], redS[WAVES];

    const int t    = threadIdx.x;
    const int b    = blockIdx.x;
    const int lane = t & 63;
    const int wv   = t >> 6;
    const int l15  = lane & 15;           // B-operand index -> output row (enc row)
    const int quad = lane >> 4;           // k-slice; with swap: d = quad*4 + r

    const float* encb = enc + (size_t)b * SS * HH;
    const int rowbase = wv * RPW;

    // Lane's enc source for tile i: row = rowbase + i*16 + l15, cols quad*8..+7.
    // Wave footprint per tile = 16 rows x 128 B contiguous -> fully coalesced.
    const float* src0 = encb + (size_t)(rowbase + l15) * HH + quad * 8;

    // ---- fill the register pipeline FIRST so loads fly during setup ----
    float4 pf[DEPTH][2];
#pragma unroll
    for (int s = 0; s < DEPTH; ++s) {
        const float* p = src0 + (size_t)s * 16 * HH;
        pf[s][0] = *(const float4*)p;
        pf[s][1] = *(const float4*)(p + 4);
    }

    // ---- A fragment (constant): Wq[d=l15][h=quad*8+j] as bf16, 4 VGPRs ----
    const float* wp = Wq + l15 * HH + quad * 8;
    const short8 wfrag = cvt_bf16x8(*(const float4*)wp, *(const float4*)(wp + 4));

    // ---- bias for d = quad*4 + r, folded into the MFMA C-in ----
    const float4 bq4 = *(const float4*)(bq + quad * 4);

    // ---- kn[d] per lane (d=l15, identical across 16-lane rows), then gather
    // the 4 values this lane needs (d = quad*4 + r) via one-time shuffles ----
    float knr0, knr1, knr2, knr3;
    {
        float a = bk[l15];
        const float* wk = Wk + l15 * HH;
#pragma unroll
        for (int h = 0; h < HH; ++h) a = fmaf(wk[h], dec[b * HH + h], a);
        float ssk = red16(a * a);
        float knV = a * (1.f / fmaxf(sqrtf(ssk), EPSI));
        knr0 = __shfl(knV, 4 * quad + 0);
        knr1 = __shfl(knV, 4 * quad + 1);
        knr2 = __shfl(knV, 4 * quad + 2);
        knr3 = __shfl(knV, 4 * quad + 3);
    }

    const int bp16 = (lane ^ 16) << 2;    // bpermute byte addrs, precomputed
    const int bp32 = (lane ^ 32) << 2;

    // ---- barrier-free streaming loop: rotate DEPTH pipeline slots ----
    float* attW = attS + rowbase;
    for (int g = 0; g < NGRP; ++g) {
#pragma unroll
        for (int s = 0; s < DEPTH; ++s) {
            const int i = g * DEPTH + s;
            // consume slot s (fine-grained vmcnt: later slots stay in flight)
            float4 p0 = pf[s][0];
            float4 p1 = pf[s][1];
            // refill slot s with tile i+DEPTH
            if (g + 1 < NGRP) {
                const float* p = src0 + (size_t)(i + DEPTH) * 16 * HH;
                pf[s][0] = *(const float4*)p;
                pf[s][1] = *(const float4*)(p + 4);
            }
            short8 efrag = cvt_bf16x8(p0, p1);

            floatx4 acc = {bq4.x, bq4.y, bq4.z, bq4.w};  // bias as C-in
            acc = __builtin_amdgcn_mfma_f32_16x16x32_bf16(wfrag, efrag, acc, 0, 0, 0);
            // acc[r] = q[d = quad*4 + r][row = i*16 + l15]

            // per-lane partial reduction over this quad's 4 d's
            float ss = 0.f, nu = 0.f;
            float qv;
            qv = acc[0]; ss = fmaf(qv, qv, ss); nu = fmaf(qv, knr0, nu);
            qv = acc[1]; ss = fmaf(qv, qv, ss); nu = fmaf(qv, knr1, nu);
            qv = acc[2]; ss = fmaf(qv, qv, ss); nu = fmaf(qv, knr2, nu);
            qv = acc[3]; ss = fmaf(qv, qv, ss); nu = fmaf(qv, knr3, nu);

            // combine the 4 quads: butterfly over lane^16, lane^32
            ss = bperm_add(bp16, ss);
            nu = bperm_add(bp16, nu);
            ss = bperm_add(bp32, ss);
            nu = bperm_add(bp32, nu);

            // att = nu / max(sqrt(ss), eps), via v_rsq (~1 ulp; eps^2 clamp)
            float ssc = fmaxf(ss, EPSI * EPSI);
            float att = nu * __builtin_amdgcn_rsqf(ssc);
            if (lane < 16) attW[i * 16 + lane] = att;  // 16 lanes, 64 B, no conflicts
        }
    }
    __syncthreads();   // the ONLY barrier before the softmax

    // ---- block log-softmax over attS[4096], 512 threads ----
    float m = -INFINITY;
#pragma unroll
    for (int i = 0; i < SS / NT; ++i) m = fmaxf(m, attS[t + i * NT]);
#pragma unroll
    for (int off = 32; off >= 1; off >>= 1) m = fmaxf(m, __shfl_down(m, off));
    if (lane == 0) redM[wv] = m;
    __syncthreads();
    float M = redM[0];
#pragma unroll
    for (int w = 1; w < WAVES; ++w) M = fmaxf(M, redM[w]);

    float sacc = 0.f;
#pragma unroll
    for (int i = 0; i < SS / NT; ++i) sacc += __expf(attS[t + i * NT] - M);
#pragma unroll
    for (int off = 32; off >= 1; off >>= 1) sacc += __shfl_down(sacc, off);
    if (lane == 0) redS[wv] = sacc;
    __syncthreads();
    float S = 0.f;
#pragma unroll
    for (int w = 0; w < WAVES; ++w) S += redS[w];
    const float logZ = M + __logf(S);

    // coalesced float4 output
    float4* ob4 = (float4*)(out + (size_t)b * SS);
#pragma unroll
    for (int i = 0; i < SS / NT / 4; ++i) {   // 2 iterations
        float4 a4 = *(const float4*)&attS[(t + i * NT) * 4];
        a4.x -= logZ; a4.y -= logZ; a4.z -= logZ; a4.w -= logZ;
        ob4[t + i * NT] = a4;
    }
}

extern "C" void kernel_launch(void* const* d_in, const int* in_sizes, int n_in,
                              void* d_out, int out_size, void* d_ws, size_t ws_size,
                              hipStream_t stream) {
    const float* dec = (const float*)d_in[0];  // [512,32]
    const float* enc = (const float*)d_in[1];  // [512,4096,32]
    const float* Wq  = (const float*)d_in[2];  // [16,32]
    const float* bq  = (const float*)d_in[3];  // [16]
    const float* Wk  = (const float*)d_in[4];  // [16,32]
    const float* bk  = (const float*)d_in[5];  // [16]
    float* out = (float*)d_out;                // [512,1,4096]

    attn_cos_logsoftmax<<<dim3(BB), dim3(NT), 0, stream>>>(dec, enc, Wq, bq, Wk, bk, out);
}